// Round 4
// baseline (523.546 us; speedup 1.0000x reference)
//
#include <hip/hip_runtime.h>
#include <math.h>

#define NN   100000
#define NE   1600000
#define DIN  128
#define DH   64
#define DOUT 40
#define BN_EPS 1e-5f
#define NBLK 98   // ceil(NN/1024)

typedef unsigned short ushort_t;
typedef unsigned int uint_t;

__device__ __forceinline__ float bf2f(ushort_t v) {
  union { uint_t u; float f; } w;
  w.u = ((uint_t)v) << 16;
  return w.f;
}
__device__ __forceinline__ ushort_t f2bf(float f) {  // RNE
  union { float f; uint_t u; } w;
  w.f = f;
  uint_t u = w.u;
  u += 0x7fffu + ((u >> 16) & 1u);
  return (ushort_t)(u >> 16);
}

// ---------------- init: hist=0, cursor=0, stats=0 ----------------
__global__ void k_init(int* __restrict__ hist, int* __restrict__ cursor,
                       float* __restrict__ stats) {
  int i = blockIdx.x * blockDim.x + threadIdx.x;
  if (i < NN) { hist[i] = 0; cursor[i] = 0; }
  if (i < 128) stats[i] = 0.0f;
}

// ---------------- int histogram over dst ----------------
__global__ void k_hist(const int* __restrict__ dst, int* __restrict__ hist) {
  int e = blockIdx.x * blockDim.x + threadIdx.x;
  if (e < NE) atomicAdd(&hist[dst[e]], 1);
}

// ---------------- dinv = rsqrt(1 + deg) ----------------
__global__ void k_dinv(const int* __restrict__ hist, float* __restrict__ dinv) {
  int i = blockIdx.x * blockDim.x + threadIdx.x;
  if (i < NN) dinv[i] = rsqrtf(1.0f + (float)hist[i]);
}

// ---------------- scan A: per-1024-block exclusive scan ----------------
__global__ void __launch_bounds__(1024) k_scanA(const int* __restrict__ hist,
                                                int* __restrict__ rowptr,
                                                int* __restrict__ btot) {
  __shared__ int sh[1024];
  int t = threadIdx.x, b = blockIdx.x;
  int i = b * 1024 + t;
  int v = (i < NN) ? hist[i] : 0;
  sh[t] = v;
  __syncthreads();
  for (int off = 1; off < 1024; off <<= 1) {
    int u = (t >= off) ? sh[t - off] : 0;
    __syncthreads();
    sh[t] += u;
    __syncthreads();
  }
  if (i < NN) rowptr[i] = sh[t] - v;
  if (t == 1023) btot[b] = sh[t];
}

// ---------------- scan B: add block offsets ----------------
__global__ void __launch_bounds__(1024) k_scanB(int* __restrict__ rowptr,
                                                const int* __restrict__ btot) {
  __shared__ int sh[128];
  int t = threadIdx.x, b = blockIdx.x;
  if (t < 128) sh[t] = (t < NBLK) ? btot[t] : 0;
  __syncthreads();
  for (int off = 1; off < 128; off <<= 1) {
    int u = (t >= off && t < 128) ? sh[t - off] : 0;
    __syncthreads();
    if (t < 128) sh[t] += u;
    __syncthreads();
  }
  int i = b * 1024 + t;
  if (i < NN && b > 0) rowptr[i] += sh[b - 1];
}

// ---------------- fill CSR ----------------
__global__ void k_fill(const int* __restrict__ src, const int* __restrict__ dst,
                       const int* __restrict__ rowptr, int* __restrict__ cursor,
                       int* __restrict__ csr) {
  int e = blockIdx.x * blockDim.x + threadIdx.x;
  if (e >= NE) return;
  int d = dst[e];
  int pos = rowptr[d] + atomicAdd(&cursor[d], 1);
  csr[pos] = src[e];
}

// ---------------- h1pre = (x0 @ W1) * dinv, stored bf16 ----------------
__global__ void __launch_bounds__(256) k_gemm1(const float* __restrict__ X,
                                               const float* __restrict__ W,
                                               const float* __restrict__ dinv,
                                               ushort_t* __restrict__ Hb) {
  int row = blockIdx.x * blockDim.x + threadIdx.x;
  if (row >= NN) return;
  float acc[DH];
#pragma unroll
  for (int j = 0; j < DH; ++j) acc[j] = 0.0f;
  const float4* xr = (const float4*)(X + (size_t)row * DIN);
  for (int k4 = 0; k4 < DIN / 4; ++k4) {
    float4 xv = xr[k4];
#pragma unroll
    for (int kk = 0; kk < 4; ++kk) {
      float xs = (&xv.x)[kk];
      const float* wr = W + (k4 * 4 + kk) * DH;  // wave-uniform -> s_load
#pragma unroll
      for (int j = 0; j < DH; ++j) acc[j] = fmaf(xs, wr[j], acc[j]);
    }
  }
  float di = dinv[row];
  uint_t pk[DH / 2];
#pragma unroll
  for (int j = 0; j < DH / 2; ++j)
    pk[j] = (uint_t)f2bf(acc[2 * j] * di) | ((uint_t)f2bf(acc[2 * j + 1] * di) << 16);
  uint4* o = (uint4*)(Hb + (size_t)row * DH);
#pragma unroll
  for (int q = 0; q < DH / 8; ++q)
    o[q] = make_uint4(pk[4 * q], pk[4 * q + 1], pk[4 * q + 2], pk[4 * q + 3]);
}

// ======== gather core: 2 nodes/wave, 32-lane halves, u32 2ch loads ========
// acc{lo,hi} accumulate channels {2*hl, 2*hl+1} of node d = base+half.
#define EDGE_LOOP(ACCLO, ACCHI)                                                \
  for (int kb = 0; kb < nmax; kb += 32) {                                      \
    int myk = kb + hl;                                                         \
    int idx = 0;                                                               \
    if (myk < n) idx = csr[st + myk];                                          \
    int lim = min(nmax - kb, 32);                                              \
    for (int s = 0; s < lim; s += 4) {                                         \
      _Pragma("unroll")                                                        \
      for (int q = 0; q < 4; ++q) {                                            \
        int sq = s + q;                                                        \
        int iq = __shfl(idx, sq + (half << 5));                                \
        if (kb + sq < n) {                                                     \
          uint_t ru = *(const uint_t*)(Hb + ((size_t)iq) * DH + 2 * hl);       \
          ACCLO += __uint_as_float(ru << 16);                                  \
          ACCHI += __uint_as_float(ru & 0xffff0000u);                          \
        }                                                                      \
      }                                                                        \
    }                                                                          \
  }

// ---------------- gather1 + fused BN stats ----------------
__global__ void __launch_bounds__(256) k_gather1(const int* __restrict__ csr,
                                                 const int* __restrict__ rowptr,
                                                 const int* __restrict__ cnt,
                                                 const float* __restrict__ dinv,
                                                 const ushort_t* __restrict__ Hb,
                                                 const float* __restrict__ bias,
                                                 float* __restrict__ Agg,
                                                 float* __restrict__ stats) {
  int lane = threadIdx.x & 63, w = threadIdx.x >> 6;
  int half = lane >> 5, hl = lane & 31;
  int wid = blockIdx.x * 4 + w;
  int nw = gridDim.x * 4;
  float2 bc = *(const float2*)(bias + 2 * hl);
  float s1lo = 0.f, s1hi = 0.f, s2lo = 0.f, s2hi = 0.f;
  for (int pr = wid; pr < NN / 2; pr += nw) {
    int d = 2 * pr + half;
    int st = rowptr[d];
    int n = cnt[d];
    float wd = dinv[d];
    int n2 = __shfl(n, lane ^ 32);
    int nmax = max(n, n2);
    uint_t su = *(const uint_t*)(Hb + (size_t)d * DH + 2 * hl);
    float acclo = __uint_as_float(su << 16);
    float acchi = __uint_as_float(su & 0xffff0000u);
    EDGE_LOOP(acclo, acchi)
    float vlo = fmaf(acclo, wd, bc.x);
    float vhi = fmaf(acchi, wd, bc.y);
    *(float2*)(Agg + (size_t)d * DH + 2 * hl) = make_float2(vlo, vhi);
    s1lo += vlo; s1hi += vhi;
    s2lo += vlo * vlo; s2hi += vhi * vhi;
  }
  __shared__ float4 red[256];
  red[threadIdx.x] = make_float4(s1lo, s1hi, s2lo, s2hi);
  __syncthreads();
  int t = threadIdx.x;
  if (t < 128) {
    int c = t & 63, which = t >> 6;  // which: 0=sum, 1=sumsq
    int l0 = c >> 1, comp = c & 1;
    float sum = 0.f;
#pragma unroll
    for (int ww = 0; ww < 4; ++ww)
#pragma unroll
      for (int h = 0; h < 2; ++h) {
        float4 r = red[ww * 64 + h * 32 + l0];
        sum += which ? (comp ? r.w : r.z) : (comp ? r.y : r.x);
      }
    atomicAdd(&stats[which * 64 + c], sum);
  }
}

// ---------------- finalize BN: scale/shift ----------------
__global__ void k_bnfinal(const float* __restrict__ stats, const float* __restrict__ g,
                          const float* __restrict__ be, float* __restrict__ scsh) {
  int c = threadIdx.x;  // 64 threads
  float mean = stats[c] * (1.0f / NN);
  float var = stats[64 + c] * (1.0f / NN) - mean * mean;
  float sc = g[c] * rsqrtf(var + BN_EPS);
  scsh[c] = sc;
  scsh[64 + c] = be[c] - mean * sc;
}

// ---------------- x1 = relu(bn(agg1)) in place; h2pre = (x1@W2)*dinv bf16 ----------------
__global__ void __launch_bounds__(256) k_bngemm2(float* __restrict__ Agg1,
                                                 const float* __restrict__ scsh,
                                                 const float* __restrict__ W2,
                                                 const float* __restrict__ dinv,
                                                 ushort_t* __restrict__ Hb) {
  int row = blockIdx.x * blockDim.x + threadIdx.x;
  if (row >= NN) return;
  float acc[DH];
#pragma unroll
  for (int j = 0; j < DH; ++j) acc[j] = 0.0f;
  float4* ar = (float4*)(Agg1 + (size_t)row * DH);
  for (int k4 = 0; k4 < DH / 4; ++k4) {
    float4 v = ar[k4];
    float x1v[4];
#pragma unroll
    for (int kk = 0; kk < 4; ++kk) {
      int k = k4 * 4 + kk;
      float t = (&v.x)[kk] * scsh[k] + scsh[64 + k];
      x1v[kk] = fmaxf(t, 0.0f);
      const float* wr = W2 + k * DH;  // wave-uniform
#pragma unroll
      for (int j = 0; j < DH; ++j) acc[j] = fmaf(x1v[kk], wr[j], acc[j]);
    }
    ar[k4] = make_float4(x1v[0], x1v[1], x1v[2], x1v[3]);  // x1 in place
  }
  float di = dinv[row];
  uint_t pk[DH / 2];
#pragma unroll
  for (int j = 0; j < DH / 2; ++j)
    pk[j] = (uint_t)f2bf(acc[2 * j] * di) | ((uint_t)f2bf(acc[2 * j + 1] * di) << 16);
  uint4* o = (uint4*)(Hb + (size_t)row * DH);
#pragma unroll
  for (int q = 0; q < DH / 8; ++q)
    o[q] = make_uint4(pk[4 * q], pk[4 * q + 1], pk[4 * q + 2], pk[4 * q + 3]);
}

// ---------------- fused gather2 + concat GEMM + log_softmax ----------------
__global__ void __launch_bounds__(256) k_g2final(const int* __restrict__ csr,
                                                 const int* __restrict__ rowptr,
                                                 const int* __restrict__ cnt,
                                                 const float* __restrict__ dinv,
                                                 const ushort_t* __restrict__ Hb,
                                                 const float* __restrict__ b2,
                                                 const float* __restrict__ X1,
                                                 const float* __restrict__ Wl,
                                                 const float* __restrict__ bl,
                                                 float* __restrict__ Out) {
  __shared__ float lx[4][2][64];
  __shared__ float la[4][2][64];
  int lane = threadIdx.x & 63, w = threadIdx.x >> 6;
  int half = lane >> 5, hl = lane & 31;
  int base = (blockIdx.x * 4 + w) * 2;  // grid exact: 12500*4*2 = NN
  int d = base + half;
  int st = rowptr[d];
  int n = cnt[d];
  float wd = dinv[d];
  int n2 = __shfl(n, lane ^ 32);
  int nmax = max(n, n2);
  float2 xv = *(const float2*)(X1 + (size_t)d * DH + 2 * hl);
  *(float2*)&lx[w][half][2 * hl] = xv;
  uint_t su = *(const uint_t*)(Hb + (size_t)d * DH + 2 * hl);
  float acclo = __uint_as_float(su << 16);
  float acchi = __uint_as_float(su & 0xffff0000u);
  EDGE_LOOP(acclo, acchi)
  float2 b2v = *(const float2*)(b2 + 2 * hl);
  *(float2*)&la[w][half][2 * hl] =
      make_float2(fmaf(acclo, wd, b2v.x), fmaf(acchi, wd, b2v.y));
  // same-wave LDS write->read (this wave wrote lx/la[w][*]): lgkmcnt ordering
  int c = lane;
#pragma unroll
  for (int p = 0; p < 2; ++p) {
    float o = -1e30f;
    if (c < DOUT) {
      o = bl[c];
#pragma unroll 8
      for (int k2 = 0; k2 < DH; ++k2) o = fmaf(lx[w][p][k2], Wl[k2 * DOUT + c], o);
#pragma unroll 8
      for (int k2 = 0; k2 < DH; ++k2) o = fmaf(la[w][p][k2], Wl[(DH + k2) * DOUT + c], o);
    }
    float m = o;
#pragma unroll
    for (int msk = 1; msk < 64; msk <<= 1) m = fmaxf(m, __shfl_xor(m, msk));
    float ee = (c < DOUT) ? __expf(o - m) : 0.0f;
    float ssum = ee;
#pragma unroll
    for (int msk = 1; msk < 64; msk <<= 1) ssum += __shfl_xor(ssum, msk);
    float lse = m + __logf(ssum);
    if (c < DOUT) Out[(size_t)(base + p) * DOUT + c] = o - lse;
  }
}

extern "C" void kernel_launch(void* const* d_in, const int* in_sizes, int n_in,
                              void* d_out, int out_size, void* d_ws, size_t ws_size,
                              hipStream_t stream) {
  const float* x0  = (const float*)d_in[0];
  const int*   ei  = (const int*)d_in[1];
  const float* W1  = (const float*)d_in[2];
  const float* b1  = (const float*)d_in[3];
  const float* g1  = (const float*)d_in[4];
  const float* be1 = (const float*)d_in[5];
  const float* W2  = (const float*)d_in[6];
  const float* b2  = (const float*)d_in[7];
  const float* Wl  = (const float*)d_in[8];
  const float* bl  = (const float*)d_in[9];
  float* out = (float*)d_out;

  const int* src = ei;
  const int* dst = ei + NE;

  // workspace layout (16B alignment preserved at each buffer)
  char* w8 = (char*)d_ws;
  int*   hist   = (int*)w8;                       // NN
  int*   cursor = hist + NN;                      // NN
  int*   rowptr = cursor + NN;                    // NN (+64 pad)
  int*   btot   = rowptr + NN + 64;               // 128
  float* stats  = (float*)(btot + 128);           // 128
  float* scsh   = stats + 128;                    // 128
  float* dinv   = scsh + 128;                     // NN (+64 pad)
  int*   csr    = (int*)(dinv + NN + 64);         // NE (+64 pad)
  ushort_t* Hb  = (ushort_t*)(csr + NE + 64);     // NN*64 bf16 (h1pre then h2pre)
  float* Agg1   = (float*)(Hb + (size_t)NN * DH); // NN*64 f32 (agg1 then x1)

  const int B = 256;
  int gN = (NN + B - 1) / B;   // 391
  int gE = (NE + B - 1) / B;   // 6250
  int gP = NN / 8;             // 12500: 4 waves/block, 2 nodes/wave, exact

  k_init<<<gN, B, 0, stream>>>(hist, cursor, stats);
  k_hist<<<gE, B, 0, stream>>>(dst, hist);
  k_dinv<<<gN, B, 0, stream>>>(hist, dinv);
  k_scanA<<<NBLK, 1024, 0, stream>>>(hist, rowptr, btot);
  k_scanB<<<NBLK, 1024, 0, stream>>>(rowptr, btot);
  k_fill<<<gE, B, 0, stream>>>(src, dst, rowptr, cursor, csr);

  k_gemm1<<<gN, B, 0, stream>>>(x0, W1, dinv, Hb);
  k_gather1<<<2048, B, 0, stream>>>(csr, rowptr, hist, dinv, Hb, b1, Agg1, stats);
  k_bnfinal<<<1, 64, 0, stream>>>(stats, g1, be1, scsh);

  k_bngemm2<<<gN, B, 0, stream>>>(Agg1, scsh, W2, dinv, Hb);
  k_g2final<<<gP, B, 0, stream>>>(csr, rowptr, hist, dinv, Hb, b2, Agg1, Wl, bl, out);
}

// Round 5
// 479.328 us; speedup vs baseline: 1.0922x; 1.0922x over previous
//
#include <hip/hip_runtime.h>
#include <hip/hip_fp8.h>
#include <math.h>

#define NN   100000
#define NE   1600000
#define DIN  128
#define DH   64
#define DOUT 40
#define BN_EPS 1e-5f
#define NBLK 98   // ceil(NN/1024)

typedef unsigned short ushort_t;
typedef unsigned int uint_t;
typedef unsigned char uchar_t;

__device__ __forceinline__ float bf2f(ushort_t v) {
  union { uint_t u; float f; } w;
  w.u = ((uint_t)v) << 16;
  return w.f;
}
__device__ __forceinline__ ushort_t f2bf(float f) {  // RNE
  union { float f; uint_t u; } w;
  w.f = f;
  uint_t u = w.u;
  u += 0x7fffu + ((u >> 16) & 1u);
  return (ushort_t)(u >> 16);
}
__device__ __forceinline__ uchar_t f2e4m3(float f) {
  __hip_fp8_e4m3 q(f);  // OCP e4m3fn, RNE + satfinite
  return (uchar_t)q.__x;
}
__device__ __forceinline__ float e4m32f(uchar_t b) {
  __hip_fp8_e4m3 q;
  q.__x = (__hip_fp8_storage_t)b;
  return (float)q;
}

// ---------------- init: hist=0, cursor=0, stats=0 ----------------
__global__ void k_init(int* __restrict__ hist, int* __restrict__ cursor,
                       float* __restrict__ stats) {
  int i = blockIdx.x * blockDim.x + threadIdx.x;
  if (i < NN) { hist[i] = 0; cursor[i] = 0; }
  if (i < 128) stats[i] = 0.0f;
}

// ---------------- int histogram over dst ----------------
__global__ void k_hist(const int* __restrict__ dst, int* __restrict__ hist) {
  int e = blockIdx.x * blockDim.x + threadIdx.x;
  if (e < NE) atomicAdd(&hist[dst[e]], 1);
}

// ---------------- dinv = rsqrt(1 + deg) ----------------
__global__ void k_dinv(const int* __restrict__ hist, float* __restrict__ dinv) {
  int i = blockIdx.x * blockDim.x + threadIdx.x;
  if (i < NN) dinv[i] = rsqrtf(1.0f + (float)hist[i]);
}

// ---------------- scan A: per-1024-block exclusive scan ----------------
__global__ void __launch_bounds__(1024) k_scanA(const int* __restrict__ hist,
                                                int* __restrict__ rowptr,
                                                int* __restrict__ btot) {
  __shared__ int sh[1024];
  int t = threadIdx.x, b = blockIdx.x;
  int i = b * 1024 + t;
  int v = (i < NN) ? hist[i] : 0;
  sh[t] = v;
  __syncthreads();
  for (int off = 1; off < 1024; off <<= 1) {
    int u = (t >= off) ? sh[t - off] : 0;
    __syncthreads();
    sh[t] += u;
    __syncthreads();
  }
  if (i < NN) rowptr[i] = sh[t] - v;
  if (t == 1023) btot[b] = sh[t];
}

// ---------------- scan B: add block offsets ----------------
__global__ void __launch_bounds__(1024) k_scanB(int* __restrict__ rowptr,
                                                const int* __restrict__ btot) {
  __shared__ int sh[128];
  int t = threadIdx.x, b = blockIdx.x;
  if (t < 128) sh[t] = (t < NBLK) ? btot[t] : 0;
  __syncthreads();
  for (int off = 1; off < 128; off <<= 1) {
    int u = (t >= off && t < 128) ? sh[t - off] : 0;
    __syncthreads();
    if (t < 128) sh[t] += u;
    __syncthreads();
  }
  int i = b * 1024 + t;
  if (i < NN && b > 0) rowptr[i] += sh[b - 1];
}

// ---------------- fill CSR ----------------
__global__ void k_fill(const int* __restrict__ src, const int* __restrict__ dst,
                       const int* __restrict__ rowptr, int* __restrict__ cursor,
                       int* __restrict__ csr) {
  int e = blockIdx.x * blockDim.x + threadIdx.x;
  if (e >= NE) return;
  int d = dst[e];
  int pos = rowptr[d] + atomicAdd(&cursor[d], 1);
  csr[pos] = src[e];
}

// ---------------- h1pre = (x0 @ W1) * dinv, stored bf16 ----------------
__global__ void __launch_bounds__(256) k_gemm1(const float* __restrict__ X,
                                               const float* __restrict__ W,
                                               const float* __restrict__ dinv,
                                               ushort_t* __restrict__ Hb) {
  int row = blockIdx.x * blockDim.x + threadIdx.x;
  if (row >= NN) return;
  float acc[DH];
#pragma unroll
  for (int j = 0; j < DH; ++j) acc[j] = 0.0f;
  const float4* xr = (const float4*)(X + (size_t)row * DIN);
  for (int k4 = 0; k4 < DIN / 4; ++k4) {
    float4 xv = xr[k4];
#pragma unroll
    for (int kk = 0; kk < 4; ++kk) {
      float xs = (&xv.x)[kk];
      const float* wr = W + (k4 * 4 + kk) * DH;  // wave-uniform -> s_load
#pragma unroll
      for (int j = 0; j < DH; ++j) acc[j] = fmaf(xs, wr[j], acc[j]);
    }
  }
  float di = dinv[row];
  uint_t pk[DH / 2];
#pragma unroll
  for (int j = 0; j < DH / 2; ++j)
    pk[j] = (uint_t)f2bf(acc[2 * j] * di) | ((uint_t)f2bf(acc[2 * j + 1] * di) << 16);
  uint4* o = (uint4*)(Hb + (size_t)row * DH);
#pragma unroll
  for (int q = 0; q < DH / 8; ++q)
    o[q] = make_uint4(pk[4 * q], pk[4 * q + 1], pk[4 * q + 2], pk[4 * q + 3]);
}

// ---------------- gather1 + fused BN stats (1 node/wave, unroll 8) ----------------
__global__ void __launch_bounds__(256) k_gather1(const int* __restrict__ csr,
                                                 const int* __restrict__ rowptr,
                                                 const int* __restrict__ cnt,
                                                 const float* __restrict__ dinv,
                                                 const ushort_t* __restrict__ Hb,
                                                 const float* __restrict__ bias,
                                                 float* __restrict__ Agg,
                                                 float* __restrict__ stats) {
  int wid = (blockIdx.x * 256 + threadIdx.x) >> 6;
  int nw = gridDim.x * 4;
  int c = threadIdx.x & 63;
  float bc = bias[c];
  float s1 = 0.0f, s2 = 0.0f;
  for (int d = wid; d < NN; d += nw) {
    int st = __builtin_amdgcn_readfirstlane(rowptr[d]);
    int n  = __builtin_amdgcn_readfirstlane(cnt[d]);
    float wd = dinv[d];
    float acc = bf2f(Hb[(size_t)d * DH + c]);  // self term (pre-scaled)
    const int* cs = csr + st;
    int k = 0;
    for (; k + 8 <= n; k += 8) {
      int i0 = cs[k], i1 = cs[k + 1], i2 = cs[k + 2], i3 = cs[k + 3];
      int i4 = cs[k + 4], i5 = cs[k + 5], i6 = cs[k + 6], i7 = cs[k + 7];
      float a0 = bf2f(Hb[(size_t)i0 * DH + c]);
      float a1 = bf2f(Hb[(size_t)i1 * DH + c]);
      float a2 = bf2f(Hb[(size_t)i2 * DH + c]);
      float a3 = bf2f(Hb[(size_t)i3 * DH + c]);
      float a4 = bf2f(Hb[(size_t)i4 * DH + c]);
      float a5 = bf2f(Hb[(size_t)i5 * DH + c]);
      float a6 = bf2f(Hb[(size_t)i6 * DH + c]);
      float a7 = bf2f(Hb[(size_t)i7 * DH + c]);
      acc += ((a0 + a1) + (a2 + a3)) + ((a4 + a5) + (a6 + a7));
    }
    for (; k < n; ++k) acc += bf2f(Hb[(size_t)cs[k] * DH + c]);
    float v = fmaf(acc, wd, bc);
    Agg[(size_t)d * DH + c] = v;
    s1 += v;
    s2 += v * v;
  }
  __shared__ float red[512];
  red[threadIdx.x] = s1;
  red[256 + threadIdx.x] = s2;
  __syncthreads();
  if (threadIdx.x < 64) {
    float a = red[c] + red[64 + c] + red[128 + c] + red[192 + c];
    float b = red[256 + c] + red[320 + c] + red[384 + c] + red[448 + c];
    atomicAdd(&stats[c], a);
    atomicAdd(&stats[64 + c], b);
  }
}

// ---------------- finalize BN: scale/shift; cvec = bl + b2@Wl_bot ----------------
__global__ void k_bnfinal(const float* __restrict__ stats, const float* __restrict__ g,
                          const float* __restrict__ be, const float* __restrict__ b2,
                          const float* __restrict__ Wl, const float* __restrict__ bl,
                          float* __restrict__ scsh, float* __restrict__ cvec) {
  int c = threadIdx.x;  // 64 threads
  float mean = stats[c] * (1.0f / NN);
  float var = stats[64 + c] * (1.0f / NN) - mean * mean;
  float sc = g[c] * rsqrtf(var + BN_EPS);
  scsh[c] = sc;
  scsh[64 + c] = be[c] - mean * sc;
  if (c < DOUT) {
    float s = bl[c];
    for (int k = 0; k < DH; ++k) s = fmaf(b2[k], Wl[(DH + k) * DOUT + c], s);
    cvec[c] = s;
  }
}

// ---- x1 = relu(bn(agg1)); y1 = x1@Wl_top + cvec; z = fp8((x1@W2)*dinv @ Wl_bot) ----
__global__ void __launch_bounds__(256) k_bngemm2(const float* __restrict__ Agg1,
                                                 const float* __restrict__ scsh,
                                                 const float* __restrict__ W2,
                                                 const float* __restrict__ dinv,
                                                 const float* __restrict__ Wl,
                                                 const float* __restrict__ cvec,
                                                 float* __restrict__ Y1,
                                                 uchar_t* __restrict__ Z) {
  int row = blockIdx.x * blockDim.x + threadIdx.x;
  if (row >= NN) return;
  float acc[DH];   // h2 accumulator
  float accy[DOUT];
#pragma unroll
  for (int j = 0; j < DH; ++j) acc[j] = 0.0f;
#pragma unroll
  for (int j = 0; j < DOUT; ++j) accy[j] = cvec[j];
  const float4* ar = (const float4*)(Agg1 + (size_t)row * DH);
  for (int k4 = 0; k4 < DH / 4; ++k4) {
    float4 v = ar[k4];
#pragma unroll
    for (int kk = 0; kk < 4; ++kk) {
      int k = k4 * 4 + kk;
      float t = (&v.x)[kk] * scsh[k] + scsh[64 + k];
      float x1 = fmaxf(t, 0.0f);
      const float* wr = W2 + k * DH;       // wave-uniform -> s_load
#pragma unroll
      for (int j = 0; j < DH; ++j) acc[j] = fmaf(x1, wr[j], acc[j]);
      const float* wt = Wl + k * DOUT;     // wave-uniform
#pragma unroll
      for (int j = 0; j < DOUT; ++j) accy[j] = fmaf(x1, wt[j], accy[j]);
    }
  }
  // y1 out (row*40 floats, 16B aligned)
  float4* yo = (float4*)(Y1 + (size_t)row * DOUT);
#pragma unroll
  for (int q = 0; q < DOUT / 4; ++q)
    yo[q] = make_float4(accy[4 * q], accy[4 * q + 1], accy[4 * q + 2], accy[4 * q + 3]);
  // z = (acc * di) @ Wl_bot, fp8
  float di = dinv[row];
  float accz[DOUT];
#pragma unroll
  for (int j = 0; j < DOUT; ++j) accz[j] = 0.0f;
#pragma unroll
  for (int k = 0; k < DH; ++k) {
    float hk = acc[k] * di;
    const float* wb = Wl + (DH + k) * DOUT;  // wave-uniform
#pragma unroll
    for (int j = 0; j < DOUT; ++j) accz[j] = fmaf(hk, wb[j], accz[j]);
  }
  uint_t zw[DOUT / 4];
#pragma unroll
  for (int q = 0; q < DOUT / 4; ++q)
    zw[q] = (uint_t)f2e4m3(accz[4 * q]) | ((uint_t)f2e4m3(accz[4 * q + 1]) << 8) |
            ((uint_t)f2e4m3(accz[4 * q + 2]) << 16) | ((uint_t)f2e4m3(accz[4 * q + 3]) << 24);
  uint2* zo = (uint2*)(Z + (size_t)row * DOUT);  // row*40 bytes, 8B aligned
#pragma unroll
  for (int q = 0; q < 5; ++q) zo[q] = make_uint2(zw[2 * q], zw[2 * q + 1]);
}

// ---------------- gather2 over fp8 z rows + log_softmax ----------------
__global__ void __launch_bounds__(256) k_g2final(const int* __restrict__ csr,
                                                 const int* __restrict__ rowptr,
                                                 const int* __restrict__ cnt,
                                                 const float* __restrict__ dinv,
                                                 const uchar_t* __restrict__ Z,
                                                 const float* __restrict__ Y1,
                                                 float* __restrict__ Out) {
  int lane = threadIdx.x & 63, w = threadIdx.x >> 6;
  int d = blockIdx.x * 4 + w;  // grid exact: 25000*4 = NN
  int st = __builtin_amdgcn_readfirstlane(rowptr[d]);
  int n  = __builtin_amdgcn_readfirstlane(cnt[d]);
  float wd = dinv[d];
  bool act = lane < DOUT;
  float acc = 0.0f;
  if (act) acc = e4m32f(Z[(size_t)d * DOUT + lane]);  // self term
  const int* cs = csr + st;
  int k = 0;
  for (; k + 8 <= n; k += 8) {
    int i0 = cs[k], i1 = cs[k + 1], i2 = cs[k + 2], i3 = cs[k + 3];
    int i4 = cs[k + 4], i5 = cs[k + 5], i6 = cs[k + 6], i7 = cs[k + 7];
    if (act) {
      uchar_t b0 = Z[(size_t)i0 * DOUT + lane];
      uchar_t b1 = Z[(size_t)i1 * DOUT + lane];
      uchar_t b2 = Z[(size_t)i2 * DOUT + lane];
      uchar_t b3 = Z[(size_t)i3 * DOUT + lane];
      uchar_t b4 = Z[(size_t)i4 * DOUT + lane];
      uchar_t b5 = Z[(size_t)i5 * DOUT + lane];
      uchar_t b6 = Z[(size_t)i6 * DOUT + lane];
      uchar_t b7 = Z[(size_t)i7 * DOUT + lane];
      acc += ((e4m32f(b0) + e4m32f(b1)) + (e4m32f(b2) + e4m32f(b3))) +
             ((e4m32f(b4) + e4m32f(b5)) + (e4m32f(b6) + e4m32f(b7)));
    }
  }
  for (; k < n; ++k) {
    int i = cs[k];
    if (act) acc += e4m32f(Z[(size_t)i * DOUT + lane]);
  }
  float o = act ? (Y1[(size_t)d * DOUT + lane] + wd * acc) : -1e30f;
  float m = o;
#pragma unroll
  for (int msk = 1; msk < 64; msk <<= 1) m = fmaxf(m, __shfl_xor(m, msk));
  float ee = act ? __expf(o - m) : 0.0f;
  float ssum = ee;
#pragma unroll
  for (int msk = 1; msk < 64; msk <<= 1) ssum += __shfl_xor(ssum, msk);
  float lse = m + __logf(ssum);
  if (act) Out[(size_t)d * DOUT + lane] = o - lse;
}

extern "C" void kernel_launch(void* const* d_in, const int* in_sizes, int n_in,
                              void* d_out, int out_size, void* d_ws, size_t ws_size,
                              hipStream_t stream) {
  const float* x0  = (const float*)d_in[0];
  const int*   ei  = (const int*)d_in[1];
  const float* W1  = (const float*)d_in[2];
  const float* b1  = (const float*)d_in[3];
  const float* g1  = (const float*)d_in[4];
  const float* be1 = (const float*)d_in[5];
  const float* W2  = (const float*)d_in[6];
  const float* b2  = (const float*)d_in[7];
  const float* Wl  = (const float*)d_in[8];
  const float* bl  = (const float*)d_in[9];
  float* out = (float*)d_out;

  const int* src = ei;
  const int* dst = ei + NE;

  // workspace layout (16B alignment preserved at each buffer)
  char* w8 = (char*)d_ws;
  int*   hist   = (int*)w8;                        // NN
  int*   cursor = hist + NN;                       // NN
  int*   rowptr = cursor + NN;                     // NN (+64 pad)
  int*   btot   = rowptr + NN + 64;                // 128
  float* stats  = (float*)(btot + 128);            // 128
  float* scsh   = stats + 128;                     // 128
  float* cvec   = scsh + 128;                      // 64
  float* dinv   = cvec + 64;                       // NN (+64 pad)
  int*   csr    = (int*)(dinv + NN + 64);          // NE (+64 pad)
  ushort_t* Hb  = (ushort_t*)(csr + NE + 64);      // NN*64 bf16 (h1pre)
  float* Agg1   = (float*)(Hb + (size_t)NN * DH);  // NN*64 f32 (agg1)
  float* Y1     = Agg1 + (size_t)NN * DH;          // NN*40 f32
  uchar_t* Z    = (uchar_t*)(Y1 + (size_t)NN * DOUT);  // NN*40 fp8

  const int B = 256;
  int gN = (NN + B - 1) / B;   // 391
  int gE = (NE + B - 1) / B;   // 6250
  int gP = NN / 4;             // 25000: 4 waves/block, 1 node/wave, exact

  k_init<<<gN, B, 0, stream>>>(hist, cursor, stats);
  k_hist<<<gE, B, 0, stream>>>(dst, hist);
  k_dinv<<<gN, B, 0, stream>>>(hist, dinv);
  k_scanA<<<NBLK, 1024, 0, stream>>>(hist, rowptr, btot);
  k_scanB<<<NBLK, 1024, 0, stream>>>(rowptr, btot);
  k_fill<<<gE, B, 0, stream>>>(src, dst, rowptr, cursor, csr);

  k_gemm1<<<gN, B, 0, stream>>>(x0, W1, dinv, Hb);
  k_gather1<<<2048, B, 0, stream>>>(csr, rowptr, hist, dinv, Hb, b1, Agg1, stats);
  k_bnfinal<<<1, 64, 0, stream>>>(stats, g1, be1, b2, Wl, bl, scsh, cvec);

  k_bngemm2<<<gN, B, 0, stream>>>(Agg1, scsh, W2, dinv, Wl, cvec, Y1, Z);
  k_g2final<<<gP, B, 0, stream>>>(csr, rowptr, hist, dinv, Z, Y1, out);
}